// Round 2
// baseline (550.994 us; speedup 1.0000x reference)
//
#include <hip/hip_runtime.h>
#include <hip/hip_fp16.h>

// HiggsMultiLinear: y = x @ W^T + bias, W dequantized from 2-dim VQ codes.
// M=4096 (2x2048), K=4096, N=4096.
// Strategy: dequant W -> fp16 hi/lo pair (scales folded in), split x -> fp16
// hi/lo, then fused 3-term split GEMM (hi*hi + hi*lo + lo*hi) in ONE K-loop
// with 16x16x32 f16 MFMA. Error ~2^-22 relative => fp32-equivalent.

#define M_TOK 4096
#define K_DIM 4096
#define N_DIM 4096

typedef _Float16 half8 __attribute__((ext_vector_type(8)));
typedef float floatx4 __attribute__((ext_vector_type(4)));

// ---------------------------------------------------------------- dequant W
__global__ void dequant_w(const int* __restrict__ c256, const int* __restrict__ c16,
                          const float* __restrict__ g256, const float* __restrict__ g16,
                          const float* __restrict__ scales,
                          _Float16* __restrict__ Whi, _Float16* __restrict__ Wlo)
{
    int idx = blockIdx.x * blockDim.x + threadIdx.x;   // one code -> 2 weights
    int row = idx >> 11;            // / 2048 codes per row
    float s = scales[row];
    int code;
    const float* g;
    if (row < 2048) { code = c256[idx]; g = g256; }
    else            { code = c16[idx - 2048*2048]; g = g16; }
    float w0 = g[2*code]     * s;
    float w1 = g[2*code + 1] * s;
    _Float16 h0 = (_Float16)w0;
    _Float16 h1 = (_Float16)w1;
    _Float16 l0 = (_Float16)(w0 - (float)h0);
    _Float16 l1 = (_Float16)(w1 - (float)h1);
    union U { _Float16 h[2]; unsigned u; };
    U uh; uh.h[0] = h0; uh.h[1] = h1;
    U ul; ul.h[0] = l0; ul.h[1] = l1;
    ((unsigned*)Whi)[idx] = uh.u;   // elem offset = row*4096 + 2j == 2*idx
    ((unsigned*)Wlo)[idx] = ul.u;
}

// ---------------------------------------------------------------- split x
__global__ void split_x_k(const float* __restrict__ x,
                          _Float16* __restrict__ xhi, _Float16* __restrict__ xlo)
{
    int idx = blockIdx.x * blockDim.x + threadIdx.x;   // per 4 floats
    float4 v = ((const float4*)x)[idx];
    _Float16 h0 = (_Float16)v.x, h1 = (_Float16)v.y,
             h2 = (_Float16)v.z, h3 = (_Float16)v.w;
    union U { _Float16 h[4]; unsigned long long u; };
    U uh; uh.h[0] = h0; uh.h[1] = h1; uh.h[2] = h2; uh.h[3] = h3;
    U ul;
    ul.h[0] = (_Float16)(v.x - (float)h0);
    ul.h[1] = (_Float16)(v.y - (float)h1);
    ul.h[2] = (_Float16)(v.z - (float)h2);
    ul.h[3] = (_Float16)(v.w - (float)h3);
    ((unsigned long long*)xhi)[idx] = uh.u;
    ((unsigned long long*)xlo)[idx] = ul.u;
}

// ---------------------------------------------------------------- GEMM
#define BM 128
#define BN 128
#define BK 32

__device__ __forceinline__ void gl2lds16(const void* g, void* l)
{
    __builtin_amdgcn_global_load_lds(
        (const __attribute__((address_space(1))) void*)g,
        (__attribute__((address_space(3))) void*)l, 16, 0, 0);
}

__global__ __launch_bounds__(256)
void gemm3(const _Float16* __restrict__ Xhi, const _Float16* __restrict__ Xlo,
           const _Float16* __restrict__ Whi, const _Float16* __restrict__ Wlo,
           const float* __restrict__ bias, float* __restrict__ C)
{
    __shared__ _Float16 AsH[BM * BK];   // 8 KB each, linear row-major [128][32]
    __shared__ _Float16 AsL[BM * BK];
    __shared__ _Float16 BsH[BN * BK];
    __shared__ _Float16 BsL[BN * BK];

    const int t    = threadIdx.x;
    const int lane = t & 63;
    const int wave = t >> 6;
    const int wr   = wave >> 1;        // 0..1 : wave row
    const int wc   = wave & 1;         // 0..1 : wave col
    const int brow = blockIdx.y * BM;
    const int bcol = blockIdx.x * BN;

    const int lrow = lane & 15;        // fragment row/col within 16
    const int lk   = (lane >> 4) * 8;  // fragment k offset

    // staging geometry: thread t covers row t/4, k (t%4)*8 within a 64-row half
    const int srow = t >> 2;
    const int sk   = (t & 3) * 8;

    floatx4 acc[4][4];
    #pragma unroll
    for (int m = 0; m < 4; ++m)
        #pragma unroll
        for (int n = 0; n < 4; ++n)
            #pragma unroll
            for (int r = 0; r < 4; ++r) acc[m][n][r] = 0.0f;

    const _Float16* AgH = Xhi + (size_t)brow * K_DIM;
    const _Float16* AgL = Xlo + (size_t)brow * K_DIM;
    const _Float16* BgH = Whi + (size_t)bcol * K_DIM;
    const _Float16* BgL = Wlo + (size_t)bcol * K_DIM;

    for (int kt = 0; kt < K_DIM; kt += BK) {
        __syncthreads();   // previous tile fully consumed before overwrite
        #pragma unroll
        for (int j = 0; j < 2; ++j) {
            const size_t go = (size_t)(j*64 + srow) * K_DIM + kt + sk;
            const int    lo = j*2048 + t*8;
            gl2lds16(AgH + go, &AsH[lo]);
            gl2lds16(AgL + go, &AsL[lo]);
            gl2lds16(BgH + go, &BsH[lo]);
            gl2lds16(BgL + go, &BsL[lo]);
        }
        __syncthreads();   // compiler drains vmcnt(0) before s_barrier

        half8 ah[4], al[4], bh[4], bl[4];
        #pragma unroll
        for (int m = 0; m < 4; ++m) {
            const int off = (wr*64 + m*16 + lrow) * BK + lk;
            ah[m] = *(const half8*)&AsH[off];
            al[m] = *(const half8*)&AsL[off];
        }
        #pragma unroll
        for (int n = 0; n < 4; ++n) {
            const int off = (wc*64 + n*16 + lrow) * BK + lk;
            bh[n] = *(const half8*)&BsH[off];
            bl[n] = *(const half8*)&BsL[off];
        }

        #pragma unroll
        for (int m = 0; m < 4; ++m)
            #pragma unroll
            for (int n = 0; n < 4; ++n) {
                acc[m][n] = __builtin_amdgcn_mfma_f32_16x16x32_f16(
                                ah[m], bh[n], acc[m][n], 0, 0, 0);
                acc[m][n] = __builtin_amdgcn_mfma_f32_16x16x32_f16(
                                ah[m], bl[n], acc[m][n], 0, 0, 0);
                acc[m][n] = __builtin_amdgcn_mfma_f32_16x16x32_f16(
                                al[m], bh[n], acc[m][n], 0, 0, 0);
            }
    }

    // epilogue: C[row][col] = acc + bias[col]
    #pragma unroll
    for (int n = 0; n < 4; ++n) {
        const int col = bcol + wc*64 + n*16 + lrow;
        const float bv = bias[col];
        #pragma unroll
        for (int m = 0; m < 4; ++m) {
            const int rbase = brow + wr*64 + m*16 + (lane >> 4) * 4;
            #pragma unroll
            for (int r = 0; r < 4; ++r)
                C[(size_t)(rbase + r) * N_DIM + col] = acc[m][n][r] + bv;
        }
    }
}

// ---------------------------------------------------------------- launch
extern "C" void kernel_launch(void* const* d_in, const int* in_sizes, int n_in,
                              void* d_out, int out_size, void* d_ws, size_t ws_size,
                              hipStream_t stream)
{
    const float* x      = (const float*)d_in[0];
    const int*   c256   = (const int*)  d_in[1];
    const int*   c16    = (const int*)  d_in[2];
    const float* g256   = (const float*)d_in[3];
    const float* g16    = (const float*)d_in[4];
    const float* scales = (const float*)d_in[5];
    const float* bias   = (const float*)d_in[6];
    float*       out    = (float*)d_out;

    char* ws = (char*)d_ws;
    const size_t SZ = (size_t)K_DIM * N_DIM * sizeof(_Float16);  // 32 MB
    _Float16* Whi = (_Float16*)(ws + 0*SZ);
    _Float16* Wlo = (_Float16*)(ws + 1*SZ);
    _Float16* Xhi = (_Float16*)(ws + 2*SZ);
    _Float16* Xlo = (_Float16*)(ws + 3*SZ);

    // dequant: 4096 rows x 2048 codes
    dequant_w<<<dim3((4096*2048)/256), dim3(256), 0, stream>>>(
        c256, c16, g256, g16, scales, Whi, Wlo);
    // split x: 4096*4096 elems, 4 per thread
    split_x_k<<<dim3((M_TOK*K_DIM/4)/256), dim3(256), 0, stream>>>(x, Xhi, Xlo);
    // GEMM: 32x32 blocks of 128x128
    gemm3<<<dim3(N_DIM/BN, M_TOK/BM), dim3(256), 0, stream>>>(
        Xhi, Xlo, Whi, Wlo, bias, out);
}

// Round 8
// 346.836 us; speedup vs baseline: 1.5886x; 1.5886x over previous
//
#include <hip/hip_runtime.h>
#include <hip/hip_fp16.h>

// HiggsMultiLinear: y = x @ W^T + bias, W dequantized from 2-dim VQ codes.
// M=4096 (2x2048), K=4096, N=4096.
// Strategy: tolerance is absmax<=2.0 vs sigma_y~64 => single-term fp16 GEMM
// suffices (err ~0.2 max, 10x margin). dequant W -> fp16 (scales folded),
// cast x -> fp16, one 16x16x32 f16 MFMA GEMM (m97 128^2 structure; the
// 3-term variant of this exact geometry passed r2 at 998 TF-equiv).
// + XCD-aware bijective block swizzle (1024 blocks % 8 == 0).

#define M_TOK 4096
#define K_DIM 4096
#define N_DIM 4096

typedef _Float16 half8 __attribute__((ext_vector_type(8)));
typedef float floatx4 __attribute__((ext_vector_type(4)));

// ---------------------------------------------------------------- dequant W
// 4 codes (=8 weights) per thread: 16B code read, 16B W write.
__global__ void dequant_w(const int* __restrict__ c256, const int* __restrict__ c16,
                          const float* __restrict__ g256, const float* __restrict__ g16,
                          const float* __restrict__ scales,
                          _Float16* __restrict__ Wh)
{
    int idx = blockIdx.x * blockDim.x + threadIdx.x;   // 4 codes per thread
    int row = idx >> 9;                                // (idx*4)/2048 codes per row
    float s = scales[row];
    int4 cd;
    const float* g;
    if (row < 2048) { cd = ((const int4*)c256)[idx]; g = g256; }
    else            { cd = ((const int4*)c16)[idx - (2048*2048/4)]; g = g16; }
    union U { _Float16 h[8]; ulong2 u; } w;
    w.h[0] = (_Float16)(g[2*cd.x]   * s);
    w.h[1] = (_Float16)(g[2*cd.x+1] * s);
    w.h[2] = (_Float16)(g[2*cd.y]   * s);
    w.h[3] = (_Float16)(g[2*cd.y+1] * s);
    w.h[4] = (_Float16)(g[2*cd.z]   * s);
    w.h[5] = (_Float16)(g[2*cd.z+1] * s);
    w.h[6] = (_Float16)(g[2*cd.w]   * s);
    w.h[7] = (_Float16)(g[2*cd.w+1] * s);
    ((ulong2*)Wh)[idx] = w.u;      // elem offset = 8*idx
}

// ---------------------------------------------------------------- cast x
// 8 floats per thread: 2x16B read, 16B write.
__global__ void cast_x(const float* __restrict__ x, _Float16* __restrict__ xh)
{
    int idx = blockIdx.x * blockDim.x + threadIdx.x;
    float4 v0 = ((const float4*)x)[2*idx];
    float4 v1 = ((const float4*)x)[2*idx + 1];
    union U { _Float16 h[8]; ulong2 u; } o;
    o.h[0] = (_Float16)v0.x; o.h[1] = (_Float16)v0.y;
    o.h[2] = (_Float16)v0.z; o.h[3] = (_Float16)v0.w;
    o.h[4] = (_Float16)v1.x; o.h[5] = (_Float16)v1.y;
    o.h[6] = (_Float16)v1.z; o.h[7] = (_Float16)v1.w;
    ((ulong2*)xh)[idx] = o.u;
}

// ---------------------------------------------------------------- GEMM
#define BM 128
#define BN 128
#define BK 32

__device__ __forceinline__ void gl2lds16(const void* g, void* l)
{
    __builtin_amdgcn_global_load_lds(
        (const __attribute__((address_space(1))) void*)g,
        (__attribute__((address_space(3))) void*)l, 16, 0, 0);
}

__global__ __launch_bounds__(256)
void gemm1(const _Float16* __restrict__ Xh, const _Float16* __restrict__ Wh,
           const float* __restrict__ bias, float* __restrict__ C)
{
    __shared__ _Float16 As[BM * BK];   // 8 KB, linear row-major [128][32]
    __shared__ _Float16 Bs[BN * BK];   // 8 KB

    // XCD-aware bijective swizzle: 1024 blocks, 8 XCDs, 128 blocks/XCD.
    // XCD x owns grid rows 4x..4x+3 (contiguous A-panels -> L2 locality).
    const int orig = blockIdx.x;           // 0..1023, round-robins XCDs
    const int wgid = (orig & 7) * 128 + (orig >> 3);
    const int bx   = wgid & 31;            // N-block
    const int by   = wgid >> 5;            // M-block

    const int t    = threadIdx.x;
    const int lane = t & 63;
    const int wave = t >> 6;
    const int wr   = wave >> 1;        // 0..1 : wave row
    const int wc   = wave & 1;         // 0..1 : wave col
    const int brow = by * BM;
    const int bcol = bx * BN;

    const int lrow = lane & 15;        // fragment row/col within 16
    const int lk   = (lane >> 4) * 8;  // fragment k offset

    // staging geometry: thread t covers row t/4, k (t%4)*8 within a 64-row half
    const int srow = t >> 2;
    const int sk   = (t & 3) * 8;

    floatx4 acc[4][4];
    #pragma unroll
    for (int m = 0; m < 4; ++m)
        #pragma unroll
        for (int n = 0; n < 4; ++n)
            #pragma unroll
            for (int r = 0; r < 4; ++r) acc[m][n][r] = 0.0f;

    const _Float16* Ag = Xh + (size_t)brow * K_DIM;
    const _Float16* Bg = Wh + (size_t)bcol * K_DIM;

    for (int kt = 0; kt < K_DIM; kt += BK) {
        __syncthreads();   // previous tile fully consumed before overwrite
        #pragma unroll
        for (int j = 0; j < 2; ++j) {
            const size_t go = (size_t)(j*64 + srow) * K_DIM + kt + sk;
            const int    lo = j*2048 + t*8;
            gl2lds16(Ag + go, &As[lo]);
            gl2lds16(Bg + go, &Bs[lo]);
        }
        __syncthreads();   // compiler drains vmcnt(0) before s_barrier

        half8 a[4], b[4];
        #pragma unroll
        for (int m = 0; m < 4; ++m)
            a[m] = *(const half8*)&As[(wr*64 + m*16 + lrow) * BK + lk];
        #pragma unroll
        for (int n = 0; n < 4; ++n)
            b[n] = *(const half8*)&Bs[(wc*64 + n*16 + lrow) * BK + lk];

        #pragma unroll
        for (int m = 0; m < 4; ++m)
            #pragma unroll
            for (int n = 0; n < 4; ++n)
                acc[m][n] = __builtin_amdgcn_mfma_f32_16x16x32_f16(
                                a[m], b[n], acc[m][n], 0, 0, 0);
    }

    // epilogue: C[row][col] = acc + bias[col]
    #pragma unroll
    for (int n = 0; n < 4; ++n) {
        const int col = bcol + wc*64 + n*16 + lrow;
        const float bv = bias[col];
        #pragma unroll
        for (int m = 0; m < 4; ++m) {
            const int rbase = brow + wr*64 + m*16 + (lane >> 4) * 4;
            #pragma unroll
            for (int r = 0; r < 4; ++r)
                C[(size_t)(rbase + r) * N_DIM + col] = acc[m][n][r] + bv;
        }
    }
}

// ---------------------------------------------------------------- launch
extern "C" void kernel_launch(void* const* d_in, const int* in_sizes, int n_in,
                              void* d_out, int out_size, void* d_ws, size_t ws_size,
                              hipStream_t stream)
{
    const float* x      = (const float*)d_in[0];
    const int*   c256   = (const int*)  d_in[1];
    const int*   c16    = (const int*)  d_in[2];
    const float* g256   = (const float*)d_in[3];
    const float* g16    = (const float*)d_in[4];
    const float* scales = (const float*)d_in[5];
    const float* bias   = (const float*)d_in[6];
    float*       out    = (float*)d_out;

    char* ws = (char*)d_ws;
    const size_t SZ = (size_t)K_DIM * N_DIM * sizeof(_Float16);  // 32 MB
    _Float16* Wh = (_Float16*)(ws + 0*SZ);
    _Float16* Xh = (_Float16*)(ws + 1*SZ);

    // dequant: 4096 rows x 2048 codes, 4 codes/thread
    dequant_w<<<dim3((4096*2048/4)/256), dim3(256), 0, stream>>>(
        c256, c16, g256, g16, scales, Wh);
    // cast x: 4096*4096 elems, 8 per thread
    cast_x<<<dim3((M_TOK*K_DIM/8)/256), dim3(256), 0, stream>>>(x, Xh);
    // GEMM: 1024 blocks (32x32 tiles of 128x128), XCD-swizzled inside
    gemm1<<<dim3(1024), dim3(256), 0, stream>>>(Xh, Wh, bias, out);
}

// Round 10
// 295.296 us; speedup vs baseline: 1.8659x; 1.1745x over previous
//
#include <hip/hip_runtime.h>
#include <hip/hip_fp16.h>

// HiggsMultiLinear: y = x @ W^T + bias, W dequantized from 2-dim VQ codes.
// M=4096 (2x2048), K=4096, N=4096.
// r10 (= r9 re-audited): 256^2-tile 4-phase/K-tile pipelined GEMM, counted
// vmcnt(4) (never 0 mid-loop), micro-tiled conflict-free LDS via pre-permuted
// global source, setprio around MFMA clusters. FIFO accounting in comments.

#define M_TOK 4096
#define K_DIM 4096
#define N_DIM 4096
#define NT    (K_DIM / 64)     // 64 K-tiles of BK=64

typedef _Float16 half8 __attribute__((ext_vector_type(8)));
typedef float floatx4 __attribute__((ext_vector_type(4)));

// ---------------------------------------------------------------- dequant W
__global__ void dequant_w(const int* __restrict__ c256, const int* __restrict__ c16,
                          const float* __restrict__ g256, const float* __restrict__ g16,
                          const float* __restrict__ scales,
                          _Float16* __restrict__ Wh)
{
    int idx = blockIdx.x * blockDim.x + threadIdx.x;   // 4 codes per thread
    int row = idx >> 9;                                // (idx*4)/2048 codes per row
    float s = scales[row];
    int4 cd;
    const float* g;
    if (row < 2048) { cd = ((const int4*)c256)[idx]; g = g256; }
    else            { cd = ((const int4*)c16)[idx - (2048*2048/4)]; g = g16; }
    union U { _Float16 h[8]; ulong2 u; } w;
    w.h[0] = (_Float16)(g[2*cd.x]   * s);
    w.h[1] = (_Float16)(g[2*cd.x+1] * s);
    w.h[2] = (_Float16)(g[2*cd.y]   * s);
    w.h[3] = (_Float16)(g[2*cd.y+1] * s);
    w.h[4] = (_Float16)(g[2*cd.z]   * s);
    w.h[5] = (_Float16)(g[2*cd.z+1] * s);
    w.h[6] = (_Float16)(g[2*cd.w]   * s);
    w.h[7] = (_Float16)(g[2*cd.w+1] * s);
    ((ulong2*)Wh)[idx] = w.u;
}

// ---------------------------------------------------------------- cast x
__global__ void cast_x(const float* __restrict__ x, _Float16* __restrict__ xh)
{
    int idx = blockIdx.x * blockDim.x + threadIdx.x;
    float4 v0 = ((const float4*)x)[2*idx];
    float4 v1 = ((const float4*)x)[2*idx + 1];
    union U { _Float16 h[8]; ulong2 u; } o;
    o.h[0] = (_Float16)v0.x; o.h[1] = (_Float16)v0.y;
    o.h[2] = (_Float16)v0.z; o.h[3] = (_Float16)v0.w;
    o.h[4] = (_Float16)v1.x; o.h[5] = (_Float16)v1.y;
    o.h[6] = (_Float16)v1.z; o.h[7] = (_Float16)v1.w;
    ((ulong2*)xh)[idx] = o.u;
}

// ---------------------------------------------------------------- GEMM
__device__ __forceinline__ void gl2lds16(const void* g, void* l)
{
    __builtin_amdgcn_global_load_lds(
        (const __attribute__((address_space(1))) void*)g,
        (__attribute__((address_space(3))) void*)l, 16, 0, 0);
}

// LDS map (halfs): buf*32768 + unit*8192 + cell*8
//   unit: 0=A-kk0, 1=B-kk0, 2=A-kk1, 3=B-kk1  (16 KB each, [R16][kb4][r16][k8])
//   cell(R,kb,r) = R*64 + kb*16 + r ; holds global (row R*16+r, k kb*8..+7)
// Stage: thread t, load L: cell idx=L*512+t (lane-linear LDS dest for gl2lds);
//   global source permuted to match (pre-swizzled-source pattern, m173).
// Phases q0..q3 per K-tile: q = (kk<<1)|half reads A[kk] rows of the wave's
//   sub-half + B[kk] (B reused q0->q1, q2->q3). Stage unit q of tile tau+1
//   at phase q.
// FIFO proof of vmcnt(4): at tau q0-wait, outstanding <= 8 loads =
//   units {A0,B0,A1,B1}(tau); need oldest 4 (A0,B0) -> vmcnt(4).
//   At q2-wait: <=8 = {A1,B1}(tau) + {A0,B0}(tau+1); need oldest 4 -> vmcnt(4).
//   Last tile: no younger loads exist -> vmcnt(0) (once, cheap).
#define STAGE(buf, unit, pan, kcol)                                          \
    { _Float16* lb = &lds[(buf)*32768 + (unit)*8192];                        \
      gl2lds16((pan) + goff0 + (kcol), lb + t*8);                            \
      gl2lds16((pan) + goff1 + (kcol), lb + (512+t)*8); }

#define RD_A(q, mm) (*(const half8*)&lds[cur*32768 + ((q)>>1)*2*8192 +       \
      ((wr*8 + ((q)&1)*4 + (mm))*64 + kbr*16 + lrow)*8])
#define RD_B(q, n)  (*(const half8*)&lds[cur*32768 + (((q)>>1)*2+1)*8192 +   \
      ((wc*4 + (n))*64 + kbr*16 + lrow)*8])

#define PHASE_MFMA(q)                                                        \
    __builtin_amdgcn_s_setprio(1);                                           \
    _Pragma("unroll")                                                        \
    for (int mm = 0; mm < 4; ++mm) {                                         \
        _Pragma("unroll")                                                    \
        for (int n = 0; n < 4; ++n)                                          \
            acc[((q)&1)*4+mm][n] = __builtin_amdgcn_mfma_f32_16x16x32_f16(   \
                a[mm], b[n], acc[((q)&1)*4+mm][n], 0, 0, 0);                 \
    }                                                                        \
    __builtin_amdgcn_s_setprio(0);

#define BOUNDARY(morev)                                                      \
    if (morev) asm volatile("s_waitcnt vmcnt(4)" ::: "memory");              \
    else       asm volatile("s_waitcnt vmcnt(0)" ::: "memory");              \
    __builtin_amdgcn_s_barrier();                                            \
    asm volatile("" ::: "memory");

__global__ __launch_bounds__(512, 2)
void gemm8p(const _Float16* __restrict__ Xh, const _Float16* __restrict__ Wh,
            const float* __restrict__ bias, float* __restrict__ C)
{
    extern __shared__ _Float16 lds[];   // 128 KB

    const int t    = threadIdx.x;
    const int lane = t & 63;
    const int w    = t >> 6;
    const int wr   = w >> 2;           // 0..1  (M-half of block tile)
    const int wc   = w & 3;            // 0..3  (N-quarter)
    const int lrow = lane & 15;
    const int kbr  = lane >> 4;        // k-octet 0..3

    // XCD-aware bijective swizzle: 256 blocks, 8 XCDs -> 32 contiguous each.
    const int swz  = (blockIdx.x & 7) * 32 + (blockIdx.x >> 3);
    const int bx   = swz & 15;
    const int by   = swz >> 4;
    const int brow = by * 256;
    const int bcol = bx * 256;

    // stage decode per load L (lane-constant across tiles)
    const int idx0 = t,        idx1 = 512 + t;
    const size_t goff0 = (size_t)((idx0 >> 6)*16 + (idx0 & 15)) * K_DIM + ((idx0 >> 4) & 3)*8;
    const size_t goff1 = (size_t)((idx1 >> 6)*16 + (idx1 & 15)) * K_DIM + ((idx1 >> 4) & 3)*8;

    const _Float16* Apan = Xh + (size_t)brow * K_DIM;
    const _Float16* Bpan = Wh + (size_t)bcol * K_DIM;

    floatx4 acc[8][4];
    #pragma unroll
    for (int m = 0; m < 8; ++m)
        #pragma unroll
        for (int n = 0; n < 4; ++n)
            #pragma unroll
            for (int r = 0; r < 4; ++r) acc[m][n][r] = 0.0f;

    // prologue: stage all 4 units of tile 0 (8 loads/thread)
    STAGE(0, 0, Apan, 0);
    STAGE(0, 1, Bpan, 0);
    STAGE(0, 2, Apan, 32);
    STAGE(0, 3, Bpan, 32);

    for (int tau = 0; tau < NT; ++tau) {
        const int  cur  = tau & 1;
        const int  nxt  = cur ^ 1;
        const int  kn   = (tau + 1) * 64;
        const bool more = (tau + 1 < NT);
        half8 a[4], b[4];

        BOUNDARY(more);                     // guards A0,B0(tau)
        // q0: kk0, sub-half 0
        #pragma unroll
        for (int n = 0; n < 4; ++n)  b[n] = RD_B(0, n);
        #pragma unroll
        for (int mm = 0; mm < 4; ++mm) a[mm] = RD_A(0, mm);
        if (more) STAGE(nxt, 0, Apan, kn);
        PHASE_MFMA(0);

        // q1: kk0, sub-half 1 (B reused)
        #pragma unroll
        for (int mm = 0; mm < 4; ++mm) a[mm] = RD_A(1, mm);
        if (more) STAGE(nxt, 1, Bpan, kn);
        PHASE_MFMA(1);

        BOUNDARY(more);                     // guards A1,B1(tau)
        // q2: kk1, sub-half 0
        #pragma unroll
        for (int n = 0; n < 4; ++n)  b[n] = RD_B(2, n);
        #pragma unroll
        for (int mm = 0; mm < 4; ++mm) a[mm] = RD_A(2, mm);
        if (more) STAGE(nxt, 2, Apan, kn + 32);
        PHASE_MFMA(2);

        // q3: kk1, sub-half 1 (B reused)
        #pragma unroll
        for (int mm = 0; mm < 4; ++mm) a[mm] = RD_A(3, mm);
        if (more) STAGE(nxt, 3, Bpan, kn + 32);
        PHASE_MFMA(3);
    }

    // epilogue: C[row][col] = acc + bias[col]
    #pragma unroll
    for (int n = 0; n < 4; ++n) {
        const int col = bcol + wc*64 + n*16 + lrow;
        const float bv = bias[col];
        #pragma unroll
        for (int m = 0; m < 8; ++m) {
            const int rbase = brow + wr*128 + m*16 + kbr*4;
            #pragma unroll
            for (int r = 0; r < 4; ++r)
                C[(size_t)(rbase + r) * N_DIM + col] = acc[m][n][r] + bv;
        }
    }
}

// ---------------------------------------------------------------- launch
extern "C" void kernel_launch(void* const* d_in, const int* in_sizes, int n_in,
                              void* d_out, int out_size, void* d_ws, size_t ws_size,
                              hipStream_t stream)
{
    const float* x      = (const float*)d_in[0];
    const int*   c256   = (const int*)  d_in[1];
    const int*   c16    = (const int*)  d_in[2];
    const float* g256   = (const float*)d_in[3];
    const float* g16    = (const float*)d_in[4];
    const float* scales = (const float*)d_in[5];
    const float* bias   = (const float*)d_in[6];
    float*       out    = (float*)d_out;

    char* ws = (char*)d_ws;
    const size_t SZ = (size_t)K_DIM * N_DIM * sizeof(_Float16);  // 32 MB
    _Float16* Wh = (_Float16*)(ws + 0*SZ);
    _Float16* Xh = (_Float16*)(ws + 1*SZ);

    // allow 128 KB dynamic LDS (host-side attribute set, capture-safe,
    // idempotent -> same work every call)
    hipFuncSetAttribute((const void*)gemm8p,
                        hipFuncAttributeMaxDynamicSharedMemorySize, 131072);

    dequant_w<<<dim3((4096*2048/4)/256), dim3(256), 0, stream>>>(
        c256, c16, g256, g16, scales, Wh);
    cast_x<<<dim3((M_TOK*K_DIM/8)/256), dim3(256), 0, stream>>>(x, Xh);
    // 256 blocks (16x16 tiles of 256x256), 512 threads, 128 KB LDS
    gemm8p<<<dim3(256), dim3(512), 131072, stream>>>(Xh, Wh, bias, out);
}